// Round 6
// baseline (385.838 us; speedup 1.0000x reference)
//
#include <hip/hip_runtime.h>
#include <hip/hip_bf16.h>

// NT-Xent (CLIP) loss, N=16384 D=256 fp32 in, 3 fp32 out.
// loss_vu = mean_i( log(sum_j exp(sim_ij)) - sim_ii ), sim = (v̂·û^T)/T
// Logits bounded by 1/T=14.29 -> no max subtraction needed.
//
// R2: XOR-swizzled LDS 128² 4-wave. 237us.
// R3/R5/R6: staging variants (gload_lds / named regs / sched_barrier pin)
//     all ~224-280us. R4: lambda capture -> scratch spill, 635us.
// R7: 8 waves (32x64/wave) -- occupancy 45% but REGRESSED to 264us: wave
//     tile shape sets LDS-read-per-FLOP; 32x64 reuse is worse (+50% DS).
// Diagnosis: no pipe >37% busy (MFMA 159k, VALU 183k, DS 197k cyc/CU);
//     ~40% is barrier/dependency stall intrinsic to staging BOTH operands.
// R8: (a) A-operand direct cache->register MFMA fragments (no As LDS, no
//     barrier coupling; halves DS traffic and staging payload);
//     (b) XCD-bijective block swizzle: each XCD owns 16 consecutive
//     by-rows -> its 1MB V panel stays L2-hot for the A stream;
//     (c) EXP2_SCALE folded into K1's V scaling (kills 268M epilogue muls;
//     acc comes out pre-scaled, epilogue = pure exp2). Diag stays fp32
//     from unscaled v,u.

#define D_DIM 256
#define BM 128
#define BN 128
#define BK 64

constexpr float INV_T = 1.0f / 0.07f;
constexpr float EXP2_SCALE = 1.44269504088896340736f / 0.07f;  // log2(e)/T

typedef __bf16 bf16x8 __attribute__((ext_vector_type(8)));
typedef float f32x4 __attribute__((ext_vector_type(4)));

// ---------------------------------------------------------------------------
// Kernel 1: L2-normalize (fp32 -> bf16), one WAVE per row (4 rows/block).
//           V is pre-scaled by EXP2_SCALE (so GEMM acc = log2e/T * v̂·û).
//           Diag contribution computed in fp32 from UNSCALED v,u.
//           Zeroes rowsum/colsum (replaces memset).
// ---------------------------------------------------------------------------
__global__ __launch_bounds__(256) void normalize_kernel(
    const float* __restrict__ img, const float* __restrict__ txt,
    __hip_bfloat16* __restrict__ Vb, __hip_bfloat16* __restrict__ Ub,
    float* __restrict__ diagarr, float* __restrict__ rowsum,
    float* __restrict__ colsum) {
  const int wave = threadIdx.x >> 6;
  const int lane = threadIdx.x & 63;
  const int row = blockIdx.x * 4 + wave;
  const size_t base = (size_t)row * D_DIM + lane * 4;

  const float4 iv = *reinterpret_cast<const float4*>(&img[base]);
  const float4 tv = *reinterpret_cast<const float4*>(&txt[base]);

  float a = iv.x * iv.x + iv.y * iv.y + iv.z * iv.z + iv.w * iv.w;
  float b = tv.x * tv.x + tv.y * tv.y + tv.z * tv.z + tv.w * tv.w;
#pragma unroll
  for (int off = 1; off < 64; off <<= 1) {
    a += __shfl_xor(a, off, 64);
    b += __shfl_xor(b, off, 64);
  }
  const float si = 1.0f / fmaxf(sqrtf(a), 1e-8f);
  const float st = 1.0f / fmaxf(sqrtf(b), 1e-8f);
  const float4 v = {iv.x * si, iv.y * si, iv.z * si, iv.w * si};
  const float4 u = {tv.x * st, tv.y * st, tv.z * st, tv.w * st};

  // V pre-scaled by EXP2_SCALE; U unscaled.
  __hip_bfloat16 vb4[4] = {
      __float2bfloat16(v.x * EXP2_SCALE), __float2bfloat16(v.y * EXP2_SCALE),
      __float2bfloat16(v.z * EXP2_SCALE), __float2bfloat16(v.w * EXP2_SCALE)};
  __hip_bfloat16 ub4[4] = {__float2bfloat16(u.x), __float2bfloat16(u.y),
                           __float2bfloat16(u.z), __float2bfloat16(u.w)};
  *reinterpret_cast<uint2*>(&Vb[base]) = *reinterpret_cast<uint2*>(vb4);
  *reinterpret_cast<uint2*>(&Ub[base]) = *reinterpret_cast<uint2*>(ub4);

  float d = v.x * u.x + v.y * u.y + v.z * u.z + v.w * u.w;
#pragma unroll
  for (int off = 1; off < 64; off <<= 1) d += __shfl_xor(d, off, 64);
  if (lane == 0) {
    diagarr[row] = d;
    rowsum[row] = 0.0f;
    colsum[row] = 0.0f;
  }
}

// ---------------------------------------------------------------------------
// Kernel 2: tiled bf16 MFMA GEMM over sim' = (log2e/T)·v̂·û^T, online
//           exp2-sum per row and per column. 128x128 tile, 4 waves of 64x64.
// A-operand: DIRECT from global (cache-resident; 64B/row x 16 rows per
//   load instr). No As LDS, no barrier coupling on the A path.
// B-operand: staged to 16KB LDS, XOR-swizzled (chunk c8 of row r stored at
//   c8^(r&7)); frag reads 2 lanes/bank = free (m136).
// XCD swizzle: 16384 wgs % 8 == 0 -> bijective; XCD k owns by in
//   [16k,16k+16) -> V panel (1MB) L2-resident per XCD.
// A-frag (16x16x32): lane holds A[m=l15][k=quad*8+j]. C/D: col=l15,
//   row=quad*4+reg (m89/m91-verified).
// ---------------------------------------------------------------------------
__global__ __launch_bounds__(256) void gemm_lse_kernel(
    const __hip_bfloat16* __restrict__ V, const __hip_bfloat16* __restrict__ U,
    float* __restrict__ rowsum, float* __restrict__ colsum) {
  __shared__ __align__(16) unsigned short Bs[BN * BK];  // 16 KB

  const int tid = threadIdx.x;
  const int lane = tid & 63;
  const int wave = tid >> 6;
  const int wm = wave >> 1;   // wave row (0..1)
  const int wn = wave & 1;    // wave col (0..1)
  const int quad = lane >> 4;
  const int l15 = lane & 15;
  const int sw = l15 & 7;     // read-swizzle factor (= frag row & 7)

  // XCD-bijective swizzle (nwg=16384, 8 XCDs, 2048 each).
  const int swz = (blockIdx.x & 7) * 2048 + (blockIdx.x >> 3);
  const int jbase = (swz & 127) * BN;  // bx: U tile
  const int ibase = (swz >> 7) * BM;   // by: V tile (16 consecutive per XCD)

  // Per-thread A base: row = ibase + wm*64 + l15, col chunk = quad*8.
  const __hip_bfloat16* VA =
      V + (size_t)(ibase + wm * 64 + l15) * D_DIM + quad * 8;

  f32x4 acc[4][4] = {};

#pragma unroll
  for (int t = 0; t < 4; ++t) {
    const int kk = t * BK;

    // ---- stage B tile (U only): 1024 x 16B chunks, 4/thread ----
#pragma unroll
    for (int q = 0; q < 4; ++q) {
      const int chunk = q * 256 + tid;
      const int row = chunk >> 3;
      const int c8 = chunk & 7;
      const int dst = row * BK + ((c8 ^ (row & 7)) << 3);  // swizzled
      *reinterpret_cast<uint4*>(&Bs[dst]) = *reinterpret_cast<const uint4*>(
          &U[(size_t)(jbase + row) * D_DIM + kk + c8 * 8]);
    }

    // ---- A fragments direct from cache (issue before the barrier so
    //      their latency hides under staging + rendezvous) ----
    bf16x8 af[4][2];
#pragma unroll
    for (int mi = 0; mi < 4; ++mi)
#pragma unroll
      for (int s = 0; s < 2; ++s)
        af[mi][s] = *reinterpret_cast<const bf16x8*>(
            VA + (size_t)mi * 16 * D_DIM + kk + s * 32);

    __syncthreads();  // B tile visible (also drains A loads -- already late)

#pragma unroll
    for (int s = 0; s < 2; ++s) {          // ks = s*32
      const int c8a = s * 4 + quad;        // logical 16B chunk
      const int pc = ((c8a ^ sw) << 3);    // swizzled short offset
      bf16x8 bfr[4];
#pragma unroll
      for (int ni = 0; ni < 4; ++ni)
        bfr[ni] = *reinterpret_cast<const bf16x8*>(
            &Bs[(wn * 64 + ni * 16 + l15) * BK + pc]);
#pragma unroll
      for (int mi = 0; mi < 4; ++mi)
#pragma unroll
        for (int ni = 0; ni < 4; ++ni)
          acc[mi][ni] = __builtin_amdgcn_mfma_f32_16x16x32_bf16(
              af[mi][s], bfr[ni], acc[mi][ni], 0, 0, 0);
    }
    __syncthreads();  // WAR guard before next B staging
  }

  // ---- epilogue: exp2 + row/col reduction ----
  // acc[mi][ni][r]: row = wm*64+mi*16+quad*4+r, col = wn*64+ni*16+l15.
  // acc pre-scaled by log2e/T (K1) -> pure exp2.
#pragma unroll
  for (int mi = 0; mi < 4; ++mi)
#pragma unroll
    for (int ni = 0; ni < 4; ++ni)
#pragma unroll
      for (int r = 0; r < 4; ++r)
        acc[mi][ni][r] = __builtin_amdgcn_exp2f(acc[mi][ni][r]);

  // Reuse Bs as fp32 scratch: rowbuf[128], colbuf[128].
  float* rowbuf = reinterpret_cast<float*>(Bs);
  float* colbuf = rowbuf + BM;
  rowbuf[tid] = 0.0f;  // 256 floats zeroed by 256 threads
  __syncthreads();

  // Row sums: reduce across 16 cols (l15 lanes), two wn halves meet in LDS.
#pragma unroll
  for (int mi = 0; mi < 4; ++mi) {
#pragma unroll
    for (int r = 0; r < 4; ++r) {
      float rs = acc[mi][0][r] + acc[mi][1][r] + acc[mi][2][r] + acc[mi][3][r];
      rs += __shfl_xor(rs, 1, 64);
      rs += __shfl_xor(rs, 2, 64);
      rs += __shfl_xor(rs, 4, 64);
      rs += __shfl_xor(rs, 8, 64);
      if (l15 == 0)
        atomicAdd(&rowbuf[wm * 64 + mi * 16 + quad * 4 + r], rs);
    }
  }
  // Col sums: reduce across 16 rows (quads), two wm halves meet in LDS.
#pragma unroll
  for (int ni = 0; ni < 4; ++ni) {
    float cs = 0.0f;
#pragma unroll
    for (int mi = 0; mi < 4; ++mi)
      cs += acc[mi][ni][0] + acc[mi][ni][1] + acc[mi][ni][2] + acc[mi][ni][3];
    cs += __shfl_xor(cs, 16, 64);
    cs += __shfl_xor(cs, 32, 64);
    if (lane < 16)
      atomicAdd(&colbuf[wn * 64 + ni * 16 + l15], cs);
  }
  __syncthreads();

  if (tid < BM)
    atomicAdd(&rowsum[ibase + tid], rowbuf[tid]);
  else
    atomicAdd(&colsum[jbase + tid - BM], colbuf[tid - BM]);
}

// ---------------------------------------------------------------------------
// Kernel 3: finalize — mean(log(rowsum)), mean(log(colsum)), mean(diag).
// ---------------------------------------------------------------------------
__global__ __launch_bounds__(1024) void finalize_kernel(
    const float* __restrict__ rowsum, const float* __restrict__ colsum,
    const float* __restrict__ diagarr, float* __restrict__ out, int n) {
  __shared__ float sh[48];
  float sr = 0.0f, sc = 0.0f, sd = 0.0f;
  for (int i = threadIdx.x; i < n; i += 1024) {
    sr += __logf(rowsum[i]);
    sc += __logf(colsum[i]);
    sd += diagarr[i];
  }
#pragma unroll
  for (int off = 1; off < 64; off <<= 1) {
    sr += __shfl_xor(sr, off, 64);
    sc += __shfl_xor(sc, off, 64);
    sd += __shfl_xor(sd, off, 64);
  }
  const int w = threadIdx.x >> 6, lane = threadIdx.x & 63;
  if (lane == 0) { sh[w] = sr; sh[16 + w] = sc; sh[32 + w] = sd; }
  __syncthreads();
  if (threadIdx.x == 0) {
    float tr = 0.0f, tc = 0.0f, td = 0.0f;
#pragma unroll
    for (int i = 0; i < 16; ++i) {
      tr += sh[i]; tc += sh[16 + i]; td += sh[32 + i];
    }
    const float invN = 1.0f / (float)n;
    const float dm = td * INV_T * invN;   // mean diag logit
    const float lvu = tr * invN - dm;
    const float luv = tc * invN - dm;
    out[0] = 0.5f * lvu + 0.5f * luv;  // WEIGHT = 0.5
    out[1] = lvu;
    out[2] = luv;
  }
}

extern "C" void kernel_launch(void* const* d_in, const int* in_sizes, int n_in,
                              void* d_out, int out_size, void* d_ws, size_t ws_size,
                              hipStream_t stream) {
  const float* img = (const float*)d_in[0];
  const float* txt = (const float*)d_in[1];
  float* out = (float*)d_out;
  const int N = in_sizes[0] / D_DIM;  // 16384

  char* ws = (char*)d_ws;
  __hip_bfloat16* Vb = (__hip_bfloat16*)ws;
  __hip_bfloat16* Ub = (__hip_bfloat16*)(ws + (size_t)N * D_DIM * 2);
  float* rowsum = (float*)(ws + (size_t)N * D_DIM * 4);
  float* colsum = rowsum + N;
  float* diagarr = colsum + N;

  // rowsum/colsum zeroed inside normalize_kernel (ws poisoned 0xAA pre-launch)
  normalize_kernel<<<N / 4, 256, 0, stream>>>(img, txt, Vb, Ub, diagarr,
                                              rowsum, colsum);

  const int nwg = (N / BN) * (N / BM);  // 16384
  gemm_lse_kernel<<<nwg, 256, 0, stream>>>(Vb, Ub, rowsum, colsum);

  finalize_kernel<<<1, 1024, 0, stream>>>(rowsum, colsum, diagarr, out, N);
}

// Round 7
// 349.216 us; speedup vs baseline: 1.1049x; 1.1049x over previous
//
#include <hip/hip_runtime.h>
#include <hip/hip_bf16.h>

// NT-Xent (CLIP) loss, N=16384 D=256 fp32 in, 3 fp32 out.
// loss_vu = mean_i( log(sum_j exp(sim_ij)) - sim_ii ), sim = (v̂·û^T)/T
// Logits bounded by 1/T=14.29 -> no max subtraction needed.
//
// R2: XOR-swizzled LDS 128² 4-wave, 2-barrier. 237us.
// R3: gload_lds + __syncthreads (vmcnt0 drain/tile). 280us.
// R4: lambda staging -> scratch spill. 635us.
// R5/R6: reg staging +/- sched pin: ~224us. Scheduler sinks loads; 2-phase
//     barrier-locked plateau (m233: stage+drain+barrier = ~72% of loop).
// R7: 8 thin waves: occupancy up, perf DOWN (worse per-wave LDS reuse).
// R8: A direct-from-global: FETCH 37->528MB (uncoalesced frags). 332us.
// R9: T4 counted-vmcnt pipeline: double-buffered LDS (2x32KB), gload_lds
//     with pre-swizzled global source (R3-verified path), RAW s_barrier
//     (no compiler vmcnt(0) drain), depth-2 prefetch:
//       prologue: issue T0,T1
//       iter t:   s_waitcnt vmcnt(8) [own tile-t loads done] ; s_barrier
//                 compute t ; s_barrier ; issue t+2
//     Only the last tile waits vmcnt(0). Loads stay in flight ACROSS
//     barriers -- the m218 mechanism (counted vs drain0 = the whole gain).
//     Riders (verified): EXP2_SCALE folded into K1's V, __logf in K3.

#define D_DIM 256
#define BM 128
#define BN 128
#define BK 64

constexpr float INV_T = 1.0f / 0.07f;
constexpr float EXP2_SCALE = 1.44269504088896340736f / 0.07f;  // log2(e)/T

typedef __bf16 bf16x8 __attribute__((ext_vector_type(8)));
typedef float f32x4 __attribute__((ext_vector_type(4)));

#define AS1 __attribute__((address_space(1)))
#define AS3 __attribute__((address_space(3)))

// ---------------------------------------------------------------------------
// Kernel 1: L2-normalize (fp32 -> bf16), one WAVE per row (4 rows/block).
//           V pre-scaled by EXP2_SCALE (GEMM acc = log2e/T * v̂·û).
//           Diag contribution in fp32 from UNSCALED v,u. Zeroes row/colsum.
// ---------------------------------------------------------------------------
__global__ __launch_bounds__(256) void normalize_kernel(
    const float* __restrict__ img, const float* __restrict__ txt,
    __hip_bfloat16* __restrict__ Vb, __hip_bfloat16* __restrict__ Ub,
    float* __restrict__ diagarr, float* __restrict__ rowsum,
    float* __restrict__ colsum) {
  const int wave = threadIdx.x >> 6;
  const int lane = threadIdx.x & 63;
  const int row = blockIdx.x * 4 + wave;
  const size_t base = (size_t)row * D_DIM + lane * 4;

  const float4 iv = *reinterpret_cast<const float4*>(&img[base]);
  const float4 tv = *reinterpret_cast<const float4*>(&txt[base]);

  float a = iv.x * iv.x + iv.y * iv.y + iv.z * iv.z + iv.w * iv.w;
  float b = tv.x * tv.x + tv.y * tv.y + tv.z * tv.z + tv.w * tv.w;
#pragma unroll
  for (int off = 1; off < 64; off <<= 1) {
    a += __shfl_xor(a, off, 64);
    b += __shfl_xor(b, off, 64);
  }
  const float si = 1.0f / fmaxf(sqrtf(a), 1e-8f);
  const float st = 1.0f / fmaxf(sqrtf(b), 1e-8f);
  const float4 v = {iv.x * si, iv.y * si, iv.z * si, iv.w * si};
  const float4 u = {tv.x * st, tv.y * st, tv.z * st, tv.w * st};

  __hip_bfloat16 vb4[4] = {
      __float2bfloat16(v.x * EXP2_SCALE), __float2bfloat16(v.y * EXP2_SCALE),
      __float2bfloat16(v.z * EXP2_SCALE), __float2bfloat16(v.w * EXP2_SCALE)};
  __hip_bfloat16 ub4[4] = {__float2bfloat16(u.x), __float2bfloat16(u.y),
                           __float2bfloat16(u.z), __float2bfloat16(u.w)};
  *reinterpret_cast<uint2*>(&Vb[base]) = *reinterpret_cast<uint2*>(vb4);
  *reinterpret_cast<uint2*>(&Ub[base]) = *reinterpret_cast<uint2*>(ub4);

  float d = v.x * u.x + v.y * u.y + v.z * u.z + v.w * u.w;
#pragma unroll
  for (int off = 1; off < 64; off <<= 1) d += __shfl_xor(d, off, 64);
  if (lane == 0) {
    diagarr[row] = d;
    rowsum[row] = 0.0f;
    colsum[row] = 0.0f;
  }
}

// ---------------------------------------------------------------------------
// Kernel 2: tiled bf16 MFMA GEMM over sim' = (log2e/T)·v̂·û^T, online
//           exp2-sum per row and per column. 128x128 tile, 4 waves of 64x64.
// LDS: double-buffered A/B tiles (2 x (16+16) KB = 64 KB).
// Staging: global_load_lds width=16, LINEAR LDS dest (HW: wave base +
//   lane*16); XOR swizzle realized by inverse-swizzling the GLOBAL source
//   chunk (src c8 = p ^ (row&7)) -- R3-verified correct.
// Frag reads: chunk c8a of row r at swizzled pos (c8a ^ (r&7)) -> 2
//   lanes/bank = free (m136).
// Pipeline: counted vmcnt, depth 2 (see header). Raw s_barrier only.
// A-frag (16x16x32): lane holds A[m=l15][k=quad*8+j]. C/D: col=l15,
//   row=quad*4+reg (m89/m91-verified).
// ---------------------------------------------------------------------------
__global__ __launch_bounds__(256) void gemm_lse_kernel(
    const __hip_bfloat16* __restrict__ V, const __hip_bfloat16* __restrict__ U,
    float* __restrict__ rowsum, float* __restrict__ colsum) {
  __shared__ __align__(16) unsigned short LdsA[2][BM * BK];  // 2 x 16 KB
  __shared__ __align__(16) unsigned short LdsB[2][BN * BK];  // 2 x 16 KB

  const int tid = threadIdx.x;
  const int lane = tid & 63;
  const int wave = tid >> 6;
  const int wm = wave >> 1;   // wave row (0..1)
  const int wn = wave & 1;    // wave col (0..1)
  const int quad = lane >> 4;
  const int l15 = lane & 15;
  const int sw = l15 & 7;     // read-swizzle factor (= frag row & 7)
  const int ibase = blockIdx.y * BM;
  const int jbase = blockIdx.x * BN;

  // Staging addressing: chunk_q = q*256+tid, row = q*32 + (tid>>3),
  // storage pos p = tid&7; source chunk c8 = p ^ (row&7) (q*32 = 0 mod 8).
  const int r0 = tid >> 3;
  const int c8s = (tid & 7) ^ (r0 & 7);  // inverse-swizzled source chunk
  const __hip_bfloat16* VpS = V + (size_t)(ibase + r0) * D_DIM + c8s * 8;
  const __hip_bfloat16* UpS = U + (size_t)(jbase + r0) * D_DIM + c8s * 8;
  const int doff = tid * 16;  // byte offset of this thread's chunk (linear)

#define ISSUE_TILE(t)                                                        \
  do {                                                                       \
    const int kk_ = (t) * BK;                                                \
    char* dA_ = (char*)LdsA[(t) & 1] + doff;                                 \
    char* dB_ = (char*)LdsB[(t) & 1] + doff;                                 \
    _Pragma("unroll") for (int q = 0; q < 4; ++q) {                          \
      __builtin_amdgcn_global_load_lds(                                      \
          (const AS1 void*)(VpS + (size_t)q * 32 * D_DIM + kk_),             \
          (AS3 void*)(dA_ + q * 4096), 16, 0, 0);                            \
      __builtin_amdgcn_global_load_lds(                                      \
          (const AS1 void*)(UpS + (size_t)q * 32 * D_DIM + kk_),             \
          (AS3 void*)(dB_ + q * 4096), 16, 0, 0);                            \
    }                                                                        \
  } while (0)

#define WAITV(n)                                                             \
  do {                                                                       \
    asm volatile("s_waitcnt vmcnt(" #n ")" ::: "memory");                    \
    __builtin_amdgcn_sched_barrier(0);                                       \
  } while (0)

  f32x4 acc[4][4] = {};

#define COMPUTE_TILE(t)                                                      \
  do {                                                                       \
    const unsigned short* bA_ = LdsA[(t) & 1];                               \
    const unsigned short* bB_ = LdsB[(t) & 1];                               \
    _Pragma("unroll") for (int s = 0; s < 2; ++s) {                          \
      const int c8a_ = s * 4 + quad;                                         \
      const int pc_ = ((c8a_ ^ sw) << 3);                                    \
      bf16x8 af_[4], bf_[4];                                                 \
      _Pragma("unroll") for (int mi = 0; mi < 4; ++mi)                       \
          af_[mi] = *reinterpret_cast<const bf16x8*>(                        \
              &bA_[(wm * 64 + mi * 16 + l15) * BK + pc_]);                   \
      _Pragma("unroll") for (int ni = 0; ni < 4; ++ni)                       \
          bf_[ni] = *reinterpret_cast<const bf16x8*>(                        \
              &bB_[(wn * 64 + ni * 16 + l15) * BK + pc_]);                   \
      _Pragma("unroll") for (int mi = 0; mi < 4; ++mi)                       \
          _Pragma("unroll") for (int ni = 0; ni < 4; ++ni)                   \
              acc[mi][ni] = __builtin_amdgcn_mfma_f32_16x16x32_bf16(         \
                  af_[mi], bf_[ni], acc[mi][ni], 0, 0, 0);                   \
    }                                                                        \
  } while (0)

  // ---- depth-2 counted-vmcnt pipeline over 4 K-tiles ----
  ISSUE_TILE(0);
  ISSUE_TILE(1);

  WAITV(8);                         // tile 0 landed (tile 1 in flight)
  __builtin_amdgcn_s_barrier();
  COMPUTE_TILE(0);
  __builtin_amdgcn_s_barrier();     // WAR: all waves done reading buf0
  ISSUE_TILE(2);

  WAITV(8);                         // tile 1 landed (tile 2 in flight)
  __builtin_amdgcn_s_barrier();
  COMPUTE_TILE(1);
  __builtin_amdgcn_s_barrier();     // WAR: all waves done reading buf1
  ISSUE_TILE(3);

  WAITV(8);                         // tile 2 landed (tile 3 in flight)
  __builtin_amdgcn_s_barrier();
  COMPUTE_TILE(2);
  // no barrier needed: nothing writes buf0 again before the epilogue sync

  WAITV(0);                         // tile 3 landed
  __builtin_amdgcn_s_barrier();
  COMPUTE_TILE(3);

  // ---- epilogue: exp2 + row/col reduction ----
  // acc[mi][ni][r]: row = wm*64+mi*16+quad*4+r, col = wn*64+ni*16+l15.
  // acc pre-scaled by log2e/T (K1) -> pure exp2.
#pragma unroll
  for (int mi = 0; mi < 4; ++mi)
#pragma unroll
    for (int ni = 0; ni < 4; ++ni)
#pragma unroll
      for (int r = 0; r < 4; ++r)
        acc[mi][ni][r] = __builtin_amdgcn_exp2f(acc[mi][ni][r]);

  // Reuse LdsA[0] as fp32 scratch: rowbuf[128], colbuf[128].
  float* rowbuf = reinterpret_cast<float*>(LdsA[0]);
  float* colbuf = rowbuf + BM;
  __syncthreads();     // all waves past COMPUTE_TILE reads
  rowbuf[tid] = 0.0f;  // 256 floats zeroed by 256 threads
  __syncthreads();

  // Row sums: reduce across 16 cols (l15 lanes), two wn halves meet in LDS.
#pragma unroll
  for (int mi = 0; mi < 4; ++mi) {
#pragma unroll
    for (int r = 0; r < 4; ++r) {
      float rs = acc[mi][0][r] + acc[mi][1][r] + acc[mi][2][r] + acc[mi][3][r];
      rs += __shfl_xor(rs, 1, 64);
      rs += __shfl_xor(rs, 2, 64);
      rs += __shfl_xor(rs, 4, 64);
      rs += __shfl_xor(rs, 8, 64);
      if (l15 == 0)
        atomicAdd(&rowbuf[wm * 64 + mi * 16 + quad * 4 + r], rs);
    }
  }
  // Col sums: reduce across 16 rows (quads), two wm halves meet in LDS.
#pragma unroll
  for (int ni = 0; ni < 4; ++ni) {
    float cs = 0.0f;
#pragma unroll
    for (int mi = 0; mi < 4; ++mi)
      cs += acc[mi][ni][0] + acc[mi][ni][1] + acc[mi][ni][2] + acc[mi][ni][3];
    cs += __shfl_xor(cs, 16, 64);
    cs += __shfl_xor(cs, 32, 64);
    if (lane < 16)
      atomicAdd(&colbuf[wn * 64 + ni * 16 + l15], cs);
  }
  __syncthreads();

  if (tid < BM)
    atomicAdd(&rowsum[ibase + tid], rowbuf[tid]);
  else
    atomicAdd(&colsum[jbase + tid - BM], colbuf[tid - BM]);
}

// ---------------------------------------------------------------------------
// Kernel 3: finalize — mean(log(rowsum)), mean(log(colsum)), mean(diag).
// ---------------------------------------------------------------------------
__global__ __launch_bounds__(1024) void finalize_kernel(
    const float* __restrict__ rowsum, const float* __restrict__ colsum,
    const float* __restrict__ diagarr, float* __restrict__ out, int n) {
  __shared__ float sh[48];
  float sr = 0.0f, sc = 0.0f, sd = 0.0f;
  for (int i = threadIdx.x; i < n; i += 1024) {
    sr += __logf(rowsum[i]);
    sc += __logf(colsum[i]);
    sd += diagarr[i];
  }
#pragma unroll
  for (int off = 1; off < 64; off <<= 1) {
    sr += __shfl_xor(sr, off, 64);
    sc += __shfl_xor(sc, off, 64);
    sd += __shfl_xor(sd, off, 64);
  }
  const int w = threadIdx.x >> 6, lane = threadIdx.x & 63;
  if (lane == 0) { sh[w] = sr; sh[16 + w] = sc; sh[32 + w] = sd; }
  __syncthreads();
  if (threadIdx.x == 0) {
    float tr = 0.0f, tc = 0.0f, td = 0.0f;
#pragma unroll
    for (int i = 0; i < 16; ++i) {
      tr += sh[i]; tc += sh[16 + i]; td += sh[32 + i];
    }
    const float invN = 1.0f / (float)n;
    const float dm = td * INV_T * invN;   // mean diag logit
    const float lvu = tr * invN - dm;
    const float luv = tc * invN - dm;
    out[0] = 0.5f * lvu + 0.5f * luv;  // WEIGHT = 0.5
    out[1] = lvu;
    out[2] = luv;
  }
}

extern "C" void kernel_launch(void* const* d_in, const int* in_sizes, int n_in,
                              void* d_out, int out_size, void* d_ws, size_t ws_size,
                              hipStream_t stream) {
  const float* img = (const float*)d_in[0];
  const float* txt = (const float*)d_in[1];
  float* out = (float*)d_out;
  const int N = in_sizes[0] / D_DIM;  // 16384

  char* ws = (char*)d_ws;
  __hip_bfloat16* Vb = (__hip_bfloat16*)ws;
  __hip_bfloat16* Ub = (__hip_bfloat16*)(ws + (size_t)N * D_DIM * 2);
  float* rowsum = (float*)(ws + (size_t)N * D_DIM * 4);
  float* colsum = rowsum + N;
  float* diagarr = colsum + N;

  // rowsum/colsum zeroed inside normalize_kernel (ws poisoned 0xAA pre-launch)
  normalize_kernel<<<N / 4, 256, 0, stream>>>(img, txt, Vb, Ub, diagarr,
                                              rowsum, colsum);

  dim3 grid(N / BN, N / BM);
  gemm_lse_kernel<<<grid, 256, 0, stream>>>(Vb, Ub, rowsum, colsum);

  finalize_kernel<<<1, 1024, 0, stream>>>(rowsum, colsum, diagarr, out, N);
}